// Round 1
// baseline (2847.376 us; speedup 1.0000x reference)
//
#include <hip/hip_runtime.h>
#include <math.h>

#define BATCH 2
#define SEQ   2048
#define HID   1024
#define NHEAD 16
#define DHEAD 64
#define MROWS (BATCH*SEQ)      // 4096
#define QK_SCALE 0.125f        // 1/sqrt(64)

// ---------------------------------------------------------------------------
// Generic tiled GEMM: C[M,N] = A[M,K] @ W[K,N] + bias[N]   (fp32)
// 64x64 block tile, 16 K-tile, 4x4 per-thread micro-tile, 256 threads.
// ---------------------------------------------------------------------------
__global__ __launch_bounds__(256) void gemm_bias_kernel(
    const float* __restrict__ A, const float* __restrict__ W,
    const float* __restrict__ bias, float* __restrict__ C,
    int M, int N, int K)
{
    __shared__ float As[16][68];   // As[k][m], +4 pad
    __shared__ float Bs[16][68];   // Bs[k][n]
    const int tid = threadIdx.x;
    const int tx = tid & 15, ty = tid >> 4;
    const int m0 = blockIdx.x * 64, n0 = blockIdx.y * 64;

    const int am = tid >> 2;           // 0..63
    const int ak = (tid & 3) << 2;     // 0,4,8,12
    const int bk = tid >> 4;           // 0..15
    const int bn = (tid & 15) << 2;    // 0..60

    float c[4][4];
#pragma unroll
    for (int i = 0; i < 4; i++)
#pragma unroll
        for (int j = 0; j < 4; j++) c[i][j] = 0.f;

    for (int kc = 0; kc < K; kc += 16) {
        const float4 av = *(const float4*)&A[(size_t)(m0 + am) * K + kc + ak];
        const float4 bv = *(const float4*)&W[(size_t)(kc + bk) * N + n0 + bn];
        As[ak + 0][am] = av.x; As[ak + 1][am] = av.y;
        As[ak + 2][am] = av.z; As[ak + 3][am] = av.w;
        *(float4*)&Bs[bk][bn] = bv;
        __syncthreads();
#pragma unroll
        for (int kk = 0; kk < 16; kk++) {
            float a4[4], b4[4];
            *(float4*)a4 = *(const float4*)&As[kk][ty << 2];
            *(float4*)b4 = *(const float4*)&Bs[kk][tx << 2];
#pragma unroll
            for (int i = 0; i < 4; i++)
#pragma unroll
                for (int j = 0; j < 4; j++) c[i][j] += a4[i] * b4[j];
        }
        __syncthreads();
    }

    const float4 bb = *(const float4*)&bias[n0 + (tx << 2)];
#pragma unroll
    for (int i = 0; i < 4; i++) {
        float4 o;
        o.x = c[i][0] + bb.x; o.y = c[i][1] + bb.y;
        o.z = c[i][2] + bb.z; o.w = c[i][3] + bb.w;
        *(float4*)&C[(size_t)(m0 + (ty << 2) + i) * N + n0 + (tx << 2)] = o;
    }
}

// ---------------------------------------------------------------------------
// threshold[b,l] = sum_h qp*kp*Wt[h] + bt   — one wave per row
// ---------------------------------------------------------------------------
__global__ __launch_bounds__(256) void threshold_kernel(
    const float* __restrict__ qp, const float* __restrict__ kp,
    const float* __restrict__ Wt, const float* __restrict__ bt,
    float* __restrict__ thr)
{
    const int w = threadIdx.x >> 6, lane = threadIdx.x & 63;
    const int row = blockIdx.x * 4 + w;
    const float* qr = qp + (size_t)row * HID;
    const float* kr = kp + (size_t)row * HID;
    float s = 0.f;
#pragma unroll
    for (int i = 0; i < HID; i += 64) s += qr[i + lane] * kr[i + lane] * Wt[i + lane];
#pragma unroll
    for (int off = 32; off > 0; off >>= 1) s += __shfl_xor(s, off, 64);
    if (lane == 0) thr[row] = s + bt[0];
}

// ---------------------------------------------------------------------------
// Flash pass 1: per (b,h,q) row — online softmax, write normalized atted
// (in [B,L,H] layout) plus per-row m,l for the colsum pass.
// Block = 4 waves = 4 q rows; K/V staged in 64-row chunks.
// ---------------------------------------------------------------------------
__global__ __launch_bounds__(256) void flash_fwd_kernel(
    const float* __restrict__ qp, const float* __restrict__ kp,
    const float* __restrict__ vp, const unsigned char* __restrict__ mask,
    float* __restrict__ att, float* __restrict__ mout, float* __restrict__ lout)
{
    const int b = blockIdx.z, h = blockIdx.y;
    const int tid = threadIdx.x;
    const int w = tid >> 6, lane = tid & 63;
    const int q = blockIdx.x * 4 + w;

    __shared__ float Ks[64][68];
    __shared__ float Vs[64][68];
    __shared__ float qs[4][64];
    __shared__ float ps[4][64];

    const size_t headoff = (size_t)h * DHEAD;
    qs[w][lane] = qp[((size_t)b * SEQ + q) * HID + headoff + lane];

    float m = -1e30f, l = 0.f, acc = 0.f;   // lane owns dim d = lane

    for (int kc = 0; kc < SEQ; kc += 64) {
        __syncthreads();
        for (int i = tid; i < 1024; i += 256) {
            const int r = i >> 4, d4 = (i & 15) << 2;
            const size_t g = ((size_t)b * SEQ + kc + r) * HID + headoff + d4;
            *(float4*)&Ks[r][d4] = *(const float4*)&kp[g];
            *(float4*)&Vs[r][d4] = *(const float4*)&vp[g];
        }
        __syncthreads();

        // score for column j = lane
        float s = 0.f;
#pragma unroll
        for (int d4 = 0; d4 < 64; d4 += 4) {
            float4 kf = *(const float4*)&Ks[lane][d4];
            float4 qf = *(const float4*)&qs[w][d4];
            s += kf.x * qf.x + kf.y * qf.y + kf.z * qf.z + kf.w * qf.w;
        }
        s *= QK_SCALE;
        if (mask[(size_t)b * SEQ + kc + lane]) s = -1e9f;

        float cm = s;
#pragma unroll
        for (int off = 32; off > 0; off >>= 1) cm = fmaxf(cm, __shfl_xor(cm, off, 64));
        const float mn = fmaxf(m, cm);
        const float p = __expf(s - mn);
        const float alpha = __expf(m - mn);
        float psum = p;
#pragma unroll
        for (int off = 32; off > 0; off >>= 1) psum += __shfl_xor(psum, off, 64);
        l = l * alpha + psum;
        m = mn;
        ps[w][lane] = p;
        __syncthreads();

        // PV: lane owns output dim d = lane
        float a2 = 0.f;
#pragma unroll 16
        for (int j = 0; j < 64; j++) a2 += ps[w][j] * Vs[j][lane];
        acc = acc * alpha + a2;
    }

    att[((size_t)b * SEQ + q) * HID + headoff + lane] = acc / l;
    if (lane == 0) {
        const size_t r = ((size_t)b * NHEAD + h) * SEQ + q;
        mout[r] = m; lout[r] = l;
    }
}

// ---------------------------------------------------------------------------
// Pass 2: recompute scores, accumulate colsum[b,k] += sum_q exp(s-m_q)/l_q
// Block owns 64 K-columns for one (b,h); loops over all q in 64-row chunks.
// ---------------------------------------------------------------------------
__global__ __launch_bounds__(256) void colsum_kernel(
    const float* __restrict__ qp, const float* __restrict__ kp,
    const unsigned char* __restrict__ mask,
    const float* __restrict__ mrow, const float* __restrict__ lrow,
    float* __restrict__ colsum)
{
    const int b = blockIdx.z, h = blockIdx.y, k0 = blockIdx.x * 64;
    const int tid = threadIdx.x;
    const int w = tid >> 6, lane = tid & 63;

    __shared__ float Ks[64][68];
    __shared__ float Qs[64][68];
    __shared__ float ml[64], ll[64];
    __shared__ float part[4][64];

    const size_t headoff = (size_t)h * DHEAD;
    for (int i = tid; i < 1024; i += 256) {
        const int r = i >> 4, d4 = (i & 15) << 2;
        *(float4*)&Ks[r][d4] =
            *(const float4*)&kp[((size_t)b * SEQ + k0 + r) * HID + headoff + d4];
    }
    const int masked = mask[(size_t)b * SEQ + k0 + lane] ? 1 : 0;
    const size_t mlbase = ((size_t)b * NHEAD + h) * SEQ;

    float csum = 0.f;
    for (int qc = 0; qc < SEQ; qc += 64) {
        __syncthreads();
        for (int i = tid; i < 1024; i += 256) {
            const int r = i >> 4, d4 = (i & 15) << 2;
            *(float4*)&Qs[r][d4] =
                *(const float4*)&qp[((size_t)b * SEQ + qc + r) * HID + headoff + d4];
        }
        if (tid < 64) {
            ml[tid] = mrow[mlbase + qc + tid];
            ll[tid] = 1.0f / lrow[mlbase + qc + tid];
        }
        __syncthreads();

        float s[16];
#pragma unroll
        for (int ri = 0; ri < 16; ri++) s[ri] = 0.f;
#pragma unroll
        for (int d4 = 0; d4 < 64; d4 += 4) {
            float4 kf = *(const float4*)&Ks[lane][d4];
#pragma unroll
            for (int ri = 0; ri < 16; ri++) {
                float4 qf = *(const float4*)&Qs[(w << 4) + ri][d4];
                s[ri] += kf.x * qf.x + kf.y * qf.y + kf.z * qf.z + kf.w * qf.w;
            }
        }
#pragma unroll
        for (int ri = 0; ri < 16; ri++) {
            float sv = s[ri] * QK_SCALE;
            if (masked) sv = -1e9f;
            csum += __expf(sv - ml[(w << 4) + ri]) * ll[(w << 4) + ri];
        }
    }
    part[w][lane] = csum;
    __syncthreads();
    if (w == 0) {
        const float t = part[0][lane] + part[1][lane] + part[2][lane] + part[3][lane];
        atomicAdd(&colsum[(size_t)b * SEQ + k0 + lane], t);
    }
}

// ---------------------------------------------------------------------------
// Gate: att[row,:] *= ((colsum[row] - thr[row]) > 0)
// ---------------------------------------------------------------------------
__global__ __launch_bounds__(256) void gate_kernel(
    float* __restrict__ att, const float* __restrict__ colsum,
    const float* __restrict__ thr)
{
    const int row = blockIdx.x;
    const float g = (colsum[row] - thr[row]) > 0.f ? 1.f : 0.f;
    float4* p = (float4*)(att + (size_t)row * HID);
    float4 v = p[threadIdx.x];
    v.x *= g; v.y *= g; v.z *= g; v.w *= g;
    p[threadIdx.x] = v;
}

// ---------------------------------------------------------------------------
extern "C" void kernel_launch(void* const* d_in, const int* in_sizes, int n_in,
                              void* d_out, int out_size, void* d_ws, size_t ws_size,
                              hipStream_t stream)
{
    const float* v  = (const float*)d_in[0];
    const float* k  = (const float*)d_in[1];
    const float* q  = (const float*)d_in[2];
    const unsigned char* mask = (const unsigned char*)d_in[3];
    const float* Wv = (const float*)d_in[4];
    const float* bv = (const float*)d_in[5];
    const float* Wk = (const float*)d_in[6];
    const float* bk = (const float*)d_in[7];
    const float* Wq = (const float*)d_in[8];
    const float* bq = (const float*)d_in[9];
    const float* Wt = (const float*)d_in[10];
    const float* bt = (const float*)d_in[11];
    const float* Wm = (const float*)d_in[12];
    const float* bm = (const float*)d_in[13];
    float* out = (float*)d_out;

    float* ws     = (float*)d_ws;
    float* qp     = ws;
    float* kp     = qp  + (size_t)MROWS * HID;
    float* vp     = kp  + (size_t)MROWS * HID;
    float* att    = vp  + (size_t)MROWS * HID;
    float* thr    = att + (size_t)MROWS * HID;
    float* mrow   = thr + MROWS;
    float* lrow   = mrow + (size_t)BATCH * NHEAD * SEQ;
    float* colsum = lrow + (size_t)BATCH * NHEAD * SEQ;

    const dim3 gg(MROWS / 64, HID / 64);
    gemm_bias_kernel<<<gg, 256, 0, stream>>>(q, Wq, bq, qp, MROWS, HID, HID);
    gemm_bias_kernel<<<gg, 256, 0, stream>>>(k, Wk, bk, kp, MROWS, HID, HID);
    gemm_bias_kernel<<<gg, 256, 0, stream>>>(v, Wv, bv, vp, MROWS, HID, HID);

    threshold_kernel<<<MROWS / 4, 256, 0, stream>>>(qp, kp, Wt, bt, thr);

    flash_fwd_kernel<<<dim3(SEQ / 4, NHEAD, BATCH), 256, 0, stream>>>(
        qp, kp, vp, mask, att, mrow, lrow);

    hipMemsetAsync(colsum, 0, MROWS * sizeof(float), stream);
    colsum_kernel<<<dim3(SEQ / 64, NHEAD, BATCH), 256, 0, stream>>>(
        qp, kp, mask, mrow, lrow, colsum);

    gate_kernel<<<MROWS, 256, 0, stream>>>(att, colsum, thr);

    gemm_bias_kernel<<<gg, 256, 0, stream>>>(att, Wm, bm, out, MROWS, HID, HID);
}

// Round 2
// 781.983 us; speedup vs baseline: 3.6412x; 3.6412x over previous
//
#include <hip/hip_runtime.h>
#include <math.h>

#define BATCH 2
#define SEQ   2048
#define HID   1024
#define NHEAD 16
#define DHEAD 64
#define MROWS (BATCH*SEQ)      // 4096
#define QK_SCALE 0.125f        // 1/sqrt(64)

typedef __attribute__((ext_vector_type(8))) short short8;
typedef __attribute__((ext_vector_type(4))) float floatx4;
#define MFMA16(a,b,c) __builtin_amdgcn_mfma_f32_16x16x32_bf16(a,b,c,0,0,0)

__device__ __forceinline__ unsigned short f2bf(float x) {
    union { float f; unsigned u; } v; v.f = x;
    unsigned r = v.u + 0x7fffu + ((v.u >> 16) & 1u);   // RNE
    return (unsigned short)(r >> 16);
}
__device__ __forceinline__ float bf2f(unsigned short s) {
    union { unsigned u; float f; } v; v.u = ((unsigned)s) << 16;
    return v.f;
}

// ---------------------------------------------------------------------------
// Tiled fp32 GEMM: C[M,N] = A[M,K] @ W[K,N] + bias.  Optional fp32 and/or
// bf16 output pointers (projections write bf16 only; final GEMM fp32 only).
// ---------------------------------------------------------------------------
__global__ __launch_bounds__(256) void gemm_bias_kernel(
    const float* __restrict__ A, const float* __restrict__ W,
    const float* __restrict__ bias, float* __restrict__ Cf,
    unsigned short* __restrict__ Cb, int M, int N, int K)
{
    __shared__ float As[16][68];
    __shared__ float Bs[16][68];
    const int tid = threadIdx.x;
    const int tx = tid & 15, ty = tid >> 4;
    const int m0 = blockIdx.x * 64, n0 = blockIdx.y * 64;

    const int am = tid >> 2;
    const int ak = (tid & 3) << 2;
    const int bk = tid >> 4;
    const int bn = (tid & 15) << 2;

    float c[4][4];
#pragma unroll
    for (int i = 0; i < 4; i++)
#pragma unroll
        for (int j = 0; j < 4; j++) c[i][j] = 0.f;

    for (int kc = 0; kc < K; kc += 16) {
        const float4 av = *(const float4*)&A[(size_t)(m0 + am) * K + kc + ak];
        const float4 bv = *(const float4*)&W[(size_t)(kc + bk) * N + n0 + bn];
        As[ak + 0][am] = av.x; As[ak + 1][am] = av.y;
        As[ak + 2][am] = av.z; As[ak + 3][am] = av.w;
        *(float4*)&Bs[bk][bn] = bv;
        __syncthreads();
#pragma unroll
        for (int kk = 0; kk < 16; kk++) {
            float a4[4], b4[4];
            *(float4*)a4 = *(const float4*)&As[kk][ty << 2];
            *(float4*)b4 = *(const float4*)&Bs[kk][tx << 2];
#pragma unroll
            for (int i = 0; i < 4; i++)
#pragma unroll
                for (int j = 0; j < 4; j++) c[i][j] += a4[i] * b4[j];
        }
        __syncthreads();
    }

    const float4 bb = *(const float4*)&bias[n0 + (tx << 2)];
#pragma unroll
    for (int i = 0; i < 4; i++) {
        float4 o;
        o.x = c[i][0] + bb.x; o.y = c[i][1] + bb.y;
        o.z = c[i][2] + bb.z; o.w = c[i][3] + bb.w;
        const size_t off = (size_t)(m0 + (ty << 2) + i) * N + n0 + (tx << 2);
        if (Cf) *(float4*)&Cf[off] = o;
        if (Cb) {
            ushort4 ub;
            ub.x = f2bf(o.x); ub.y = f2bf(o.y); ub.z = f2bf(o.z); ub.w = f2bf(o.w);
            *(ushort4*)&Cb[off] = ub;
        }
    }
}

// ---------------------------------------------------------------------------
// threshold[row] = sum_h qb*kb*Wt + bt  (bf16 inputs, fp32 accumulate)
// ---------------------------------------------------------------------------
__global__ __launch_bounds__(256) void threshold_kernel(
    const unsigned short* __restrict__ qb, const unsigned short* __restrict__ kb,
    const float* __restrict__ Wt, const float* __restrict__ bt,
    float* __restrict__ thr)
{
    const int w = threadIdx.x >> 6, lane = threadIdx.x & 63;
    const int row = blockIdx.x * 4 + w;
    const unsigned short* qr = qb + (size_t)row * HID;
    const unsigned short* kr = kb + (size_t)row * HID;
    float s = 0.f;
#pragma unroll
    for (int i = 0; i < HID; i += 64)
        s += bf2f(qr[i + lane]) * bf2f(kr[i + lane]) * Wt[i + lane];
#pragma unroll
    for (int off = 32; off > 0; off >>= 1) s += __shfl_xor(s, off, 64);
    if (lane == 0) thr[row] = s + bt[0];
}

// ---------------------------------------------------------------------------
// Pass 1 (MFMA): per (b,h), Q-tile of 64 rows/block (16 per wave).
// No max-subtraction (scores |s| < ~3): O = sum exp(s)*V, Z = sum exp(s).
// Writes normalized att (fp32, [B,L,H]) and zinv = 1/Z per (b,h,q).
// ---------------------------------------------------------------------------
__global__ __launch_bounds__(256) void flash_mfma_kernel(
    const unsigned short* __restrict__ qb, const unsigned short* __restrict__ kb,
    const unsigned short* __restrict__ vb, const unsigned char* __restrict__ mask,
    float* __restrict__ att, float* __restrict__ zinv_out)
{
    const int b = blockIdx.z, h = blockIdx.y;
    const int q0 = blockIdx.x * 64;
    const int tid = threadIdx.x;
    const int w = tid >> 6, lane = tid & 63;
    const int c = lane & 15, quad = lane >> 4;

    __shared__ unsigned short Qs[64][72];
    __shared__ unsigned short Ks[64][72];
    __shared__ unsigned short Vt[64][72];   // Vt[d][vrow]
    __shared__ unsigned short Ps[4][16][72];
    __shared__ unsigned char  maskc[64];

    const size_t hoff = (size_t)h * DHEAD;

    for (int g = tid; g < 512; g += 256) {
        const int r = g >> 3, c8 = g & 7;
        *(uint4*)&Qs[r][c8 * 8] =
            *(const uint4*)&qb[(size_t)(b * SEQ + q0 + r) * HID + hoff + c8 * 8];
    }

    floatx4 acc_o[4];
#pragma unroll
    for (int dt = 0; dt < 4; dt++) acc_o[dt] = (floatx4){0.f, 0.f, 0.f, 0.f};
    float zp[4] = {0.f, 0.f, 0.f, 0.f};

    for (int kc = 0; kc < SEQ; kc += 64) {
        __syncthreads();
        for (int g = tid; g < 512; g += 256) {
            const int r = g >> 3, c8 = g & 7;
            const size_t base = (size_t)(b * SEQ + kc + r) * HID + hoff + c8 * 8;
            *(uint4*)&Ks[r][c8 * 8] = *(const uint4*)&kb[base];
            uint4 vv = *(const uint4*)&vb[base];
            const unsigned short* sp = (const unsigned short*)&vv;
#pragma unroll
            for (int j = 0; j < 8; j++) Vt[c8 * 8 + j][r] = sp[j];
        }
        if (tid < 64) maskc[tid] = mask[(size_t)b * SEQ + kc + tid];
        __syncthreads();

        const short8 aq0 = *(const short8*)&Qs[w * 16 + c][quad * 8];
        const short8 aq1 = *(const short8*)&Qs[w * 16 + c][32 + quad * 8];

#pragma unroll
        for (int nt = 0; nt < 4; nt++) {
            const short8 bk0 = *(const short8*)&Ks[nt * 16 + c][quad * 8];
            const short8 bk1 = *(const short8*)&Ks[nt * 16 + c][32 + quad * 8];
            floatx4 s = (floatx4){0.f, 0.f, 0.f, 0.f};
            s = MFMA16(aq0, bk0, s);
            s = MFMA16(aq1, bk1, s);
            const int mk = maskc[nt * 16 + c];
#pragma unroll
            for (int r = 0; r < 4; r++) {
                const float p = mk ? 0.f : __expf(s[r] * QK_SCALE);
                zp[r] += p;
                Ps[w][quad * 4 + r][nt * 16 + c] = f2bf(p);
            }
        }

        const short8 ap0 = *(const short8*)&Ps[w][c][quad * 8];
        const short8 ap1 = *(const short8*)&Ps[w][c][32 + quad * 8];
#pragma unroll
        for (int dt = 0; dt < 4; dt++) {
            const short8 bv0 = *(const short8*)&Vt[dt * 16 + c][quad * 8];
            const short8 bv1 = *(const short8*)&Vt[dt * 16 + c][32 + quad * 8];
            acc_o[dt] = MFMA16(ap0, bv0, acc_o[dt]);
            acc_o[dt] = MFMA16(ap1, bv1, acc_o[dt]);
        }
    }

#pragma unroll
    for (int r = 0; r < 4; r++) {
        float z = zp[r];
        z += __shfl_xor(z, 1, 64); z += __shfl_xor(z, 2, 64);
        z += __shfl_xor(z, 4, 64); z += __shfl_xor(z, 8, 64);
        zp[r] = 1.0f / (z + 1e-30f);
    }

#pragma unroll
    for (int dt = 0; dt < 4; dt++)
#pragma unroll
        for (int r = 0; r < 4; r++)
            att[(size_t)(b * SEQ + q0 + w * 16 + quad * 4 + r) * HID + hoff +
                dt * 16 + c] = acc_o[dt][r] * zp[r];

    if (c == 0) {
        const size_t zb = (size_t)(b * NHEAD + h) * SEQ + q0 + w * 16 + quad * 4;
#pragma unroll
        for (int r = 0; r < 4; r++) zinv_out[zb + r] = zp[r];
    }
}

// ---------------------------------------------------------------------------
// Pass 2 (MFMA): block owns 64 K-cols of one (b,h); sweeps Q chunks computing
// S^T = K·Q^T, accumulates colsum_k += exp(s)*zinv_q; atomicAdd over heads.
// ---------------------------------------------------------------------------
__global__ __launch_bounds__(256) void colsum_mfma_kernel(
    const unsigned short* __restrict__ qb, const unsigned short* __restrict__ kb,
    const unsigned char* __restrict__ mask, const float* __restrict__ zinv,
    float* __restrict__ colsum)
{
    const int b = blockIdx.z, h = blockIdx.y, k0 = blockIdx.x * 64;
    const int tid = threadIdx.x;
    const int w = tid >> 6, lane = tid & 63;
    const int c = lane & 15, quad = lane >> 4;

    __shared__ unsigned short Ks[64][72];
    __shared__ unsigned short Qs[64][72];
    __shared__ float zs[64];
    __shared__ unsigned char maskc[64];

    const size_t hoff = (size_t)h * DHEAD;
    for (int g = tid; g < 512; g += 256) {
        const int r = g >> 3, c8 = g & 7;
        *(uint4*)&Ks[r][c8 * 8] =
            *(const uint4*)&kb[(size_t)(b * SEQ + k0 + r) * HID + hoff + c8 * 8];
    }
    if (tid < 64) maskc[tid] = mask[(size_t)b * SEQ + k0 + tid];

    float cs[4] = {0.f, 0.f, 0.f, 0.f};
    const size_t zbase = (size_t)(b * NHEAD + h) * SEQ;

    for (int qc = 0; qc < SEQ; qc += 64) {
        __syncthreads();
        for (int g = tid; g < 512; g += 256) {
            const int r = g >> 3, c8 = g & 7;
            *(uint4*)&Qs[r][c8 * 8] =
                *(const uint4*)&qb[(size_t)(b * SEQ + qc + r) * HID + hoff + c8 * 8];
        }
        if (tid < 64) zs[tid] = zinv[zbase + qc + tid];
        __syncthreads();

        const short8 ak0 = *(const short8*)&Ks[w * 16 + c][quad * 8];
        const short8 ak1 = *(const short8*)&Ks[w * 16 + c][32 + quad * 8];
#pragma unroll
        for (int qt = 0; qt < 4; qt++) {
            const short8 bq0 = *(const short8*)&Qs[qt * 16 + c][quad * 8];
            const short8 bq1 = *(const short8*)&Qs[qt * 16 + c][32 + quad * 8];
            floatx4 s = (floatx4){0.f, 0.f, 0.f, 0.f};
            s = MFMA16(ak0, bq0, s);
            s = MFMA16(ak1, bq1, s);
            const float zi = zs[qt * 16 + c];
#pragma unroll
            for (int r = 0; r < 4; r++) {
                const float p = maskc[w * 16 + quad * 4 + r] ? 0.f
                                : __expf(s[r] * QK_SCALE);
                cs[r] += p * zi;
            }
        }
    }

#pragma unroll
    for (int r = 0; r < 4; r++) {
        float v = cs[r];
        v += __shfl_xor(v, 1, 64); v += __shfl_xor(v, 2, 64);
        v += __shfl_xor(v, 4, 64); v += __shfl_xor(v, 8, 64);
        if (c == 0)
            atomicAdd(&colsum[(size_t)b * SEQ + k0 + w * 16 + quad * 4 + r], v);
    }
}

// ---------------------------------------------------------------------------
// Gate: att[row,:] *= ((colsum[row] - thr[row]) > 0)
// ---------------------------------------------------------------------------
__global__ __launch_bounds__(256) void gate_kernel(
    float* __restrict__ att, const float* __restrict__ colsum,
    const float* __restrict__ thr)
{
    const int row = blockIdx.x;
    const float g = (colsum[row] - thr[row]) > 0.f ? 1.f : 0.f;
    float4* p = (float4*)(att + (size_t)row * HID);
    float4 v = p[threadIdx.x];
    v.x *= g; v.y *= g; v.z *= g; v.w *= g;
    p[threadIdx.x] = v;
}

// ---------------------------------------------------------------------------
extern "C" void kernel_launch(void* const* d_in, const int* in_sizes, int n_in,
                              void* d_out, int out_size, void* d_ws, size_t ws_size,
                              hipStream_t stream)
{
    const float* v  = (const float*)d_in[0];
    const float* k  = (const float*)d_in[1];
    const float* q  = (const float*)d_in[2];
    const unsigned char* mask = (const unsigned char*)d_in[3];
    const float* Wv = (const float*)d_in[4];
    const float* bv = (const float*)d_in[5];
    const float* Wk = (const float*)d_in[6];
    const float* bk = (const float*)d_in[7];
    const float* Wq = (const float*)d_in[8];
    const float* bq = (const float*)d_in[9];
    const float* Wt = (const float*)d_in[10];
    const float* bt = (const float*)d_in[11];
    const float* Wm = (const float*)d_in[12];
    const float* bm = (const float*)d_in[13];
    float* out = (float*)d_out;

    float* att          = (float*)d_ws;                       // MROWS*HID f32
    unsigned short* qb  = (unsigned short*)(att + (size_t)MROWS * HID);
    unsigned short* kb2 = qb  + (size_t)MROWS * HID;
    unsigned short* vb2 = kb2 + (size_t)MROWS * HID;
    float* thr          = (float*)(vb2 + (size_t)MROWS * HID);
    float* zinv         = thr + MROWS;
    float* colsum       = zinv + (size_t)BATCH * NHEAD * SEQ;

    const dim3 gg(MROWS / 64, HID / 64);
    gemm_bias_kernel<<<gg, 256, 0, stream>>>(q, Wq, bq, nullptr, qb,  MROWS, HID, HID);
    gemm_bias_kernel<<<gg, 256, 0, stream>>>(k, Wk, bk, nullptr, kb2, MROWS, HID, HID);
    gemm_bias_kernel<<<gg, 256, 0, stream>>>(v, Wv, bv, nullptr, vb2, MROWS, HID, HID);

    threshold_kernel<<<MROWS / 4, 256, 0, stream>>>(qb, kb2, Wt, bt, thr);

    flash_mfma_kernel<<<dim3(SEQ / 64, NHEAD, BATCH), 256, 0, stream>>>(
        qb, kb2, vb2, mask, att, zinv);

    hipMemsetAsync(colsum, 0, MROWS * sizeof(float), stream);
    colsum_mfma_kernel<<<dim3(SEQ / 64, NHEAD, BATCH), 256, 0, stream>>>(
        qb, kb2, mask, zinv, colsum);

    gate_kernel<<<MROWS, 256, 0, stream>>>(att, colsum, thr);

    gemm_bias_kernel<<<gg, 256, 0, stream>>>(att, Wm, bm, out, nullptr, MROWS, HID, HID);
}

// Round 3
// 378.676 us; speedup vs baseline: 7.5193x; 2.0650x over previous
//
#include <hip/hip_runtime.h>
#include <math.h>

#define BATCH 2
#define SEQ   2048
#define HID   1024
#define NHEAD 16
#define DHEAD 64
#define MROWS (BATCH*SEQ)      // 4096
#define QK_SCALE 0.125f        // 1/sqrt(64)

typedef __attribute__((ext_vector_type(8))) short short8;
typedef __attribute__((ext_vector_type(4))) float floatx4;
#define MFMA16(a,b,c) __builtin_amdgcn_mfma_f32_16x16x32_bf16(a,b,c,0,0,0)

__device__ __forceinline__ unsigned short f2bf(float x) {
    union { float f; unsigned u; } v; v.f = x;
    unsigned r = v.u + 0x7fffu + ((v.u >> 16) & 1u);   // RNE
    return (unsigned short)(r >> 16);
}
__device__ __forceinline__ float bf2f(unsigned short s) {
    union { unsigned u; float f; } v; v.u = ((unsigned)s) << 16;
    return v.f;
}

// ---------------------------------------------------------------------------
// fp32 -> bf16 bulk convert (8 elems/thread)
// ---------------------------------------------------------------------------
__global__ __launch_bounds__(256) void cvt_bf16_kernel(
    const float* __restrict__ in, unsigned short* __restrict__ out)
{
    const size_t i = ((size_t)blockIdx.x * 256 + threadIdx.x) * 8;
    const float4 a = *(const float4*)&in[i];
    const float4 b = *(const float4*)&in[i + 4];
    ushort4 u0, u1;
    u0.x = f2bf(a.x); u0.y = f2bf(a.y); u0.z = f2bf(a.z); u0.w = f2bf(a.w);
    u1.x = f2bf(b.x); u1.y = f2bf(b.y); u1.z = f2bf(b.z); u1.w = f2bf(b.w);
    *(ushort4*)&out[i] = u0;
    *(ushort4*)&out[i + 4] = u1;
}

// ---------------------------------------------------------------------------
// W[K][N] fp32 -> Wt[N][K] bf16, 64x64 LDS tile transpose
// ---------------------------------------------------------------------------
__global__ __launch_bounds__(256) void wtrans_kernel(
    const float* __restrict__ W, unsigned short* __restrict__ Wt)
{
    __shared__ float T[64][68];
    const int tid = threadIdx.x;
    const int k0 = blockIdx.x * 64, n0 = blockIdx.y * 64;
#pragma unroll
    for (int it = 0; it < 4; it++) {
        const int id = it * 256 + tid;
        const int r = id >> 4, c4 = (id & 15) << 2;
        *(float4*)&T[r][c4] = *(const float4*)&W[(size_t)(k0 + r) * HID + n0 + c4];
    }
    __syncthreads();
#pragma unroll
    for (int it = 0; it < 2; it++) {
        const int id = it * 256 + tid;
        const int n = id >> 3, k8 = (id & 7) << 3;
        ushort4 u0, u1;
        u0.x = f2bf(T[k8 + 0][n]); u0.y = f2bf(T[k8 + 1][n]);
        u0.z = f2bf(T[k8 + 2][n]); u0.w = f2bf(T[k8 + 3][n]);
        u1.x = f2bf(T[k8 + 4][n]); u1.y = f2bf(T[k8 + 5][n]);
        u1.z = f2bf(T[k8 + 6][n]); u1.w = f2bf(T[k8 + 7][n]);
        const size_t o = (size_t)(n0 + n) * HID + k0 + k8;
        *(ushort4*)&Wt[o] = u0;
        *(ushort4*)&Wt[o + 4] = u1;
    }
}

// ---------------------------------------------------------------------------
// vb[B*SEQ][HID] bf16 -> vt[B][NH][DH][SEQ] bf16 (per-head transpose)
// ---------------------------------------------------------------------------
__global__ __launch_bounds__(256) void vtrans_kernel(
    const unsigned short* __restrict__ vb, unsigned short* __restrict__ vt)
{
    __shared__ unsigned short T[64][72];
    const int b = blockIdx.z, h = blockIdx.y, l0 = blockIdx.x * 64;
    const int tid = threadIdx.x;
#pragma unroll
    for (int it = 0; it < 2; it++) {
        const int id = it * 256 + tid;
        const int l = id >> 3, c8 = (id & 7) << 3;
        *(uint4*)&T[l][c8] =
            *(const uint4*)&vb[(size_t)(b * SEQ + l0 + l) * HID + h * DHEAD + c8];
    }
    __syncthreads();
#pragma unroll
    for (int it = 0; it < 2; it++) {
        const int id = it * 256 + tid;
        const int d = id >> 3, l8 = (id & 7) << 3;
        ushort4 u0, u1;
        u0.x = T[l8 + 0][d]; u0.y = T[l8 + 1][d];
        u0.z = T[l8 + 2][d]; u0.w = T[l8 + 3][d];
        u1.x = T[l8 + 4][d]; u1.y = T[l8 + 5][d];
        u1.z = T[l8 + 6][d]; u1.w = T[l8 + 7][d];
        const size_t o = ((size_t)(b * NHEAD + h) * DHEAD + d) * SEQ + l0 + l8;
        *(ushort4*)&vt[o] = u0;
        *(ushort4*)&vt[o + 4] = u1;
    }
}

// ---------------------------------------------------------------------------
// MFMA GEMM: C[M,N] = A[M,K](bf16) @ Bt[N,K](bf16)^T + bias, fp32 accum.
// 128x128 tile, BK=64, 4 waves in 2x2, 4x4 MFMA tiles per wave.
// ---------------------------------------------------------------------------
__global__ __launch_bounds__(256) void gemm_mfma_kernel(
    const unsigned short* __restrict__ A, const unsigned short* __restrict__ Bt,
    const float* __restrict__ bias, float* __restrict__ Cf,
    unsigned short* __restrict__ Cb, int M, int N, int K)
{
    __shared__ unsigned short As[128][72];
    __shared__ unsigned short Bs[128][72];
    const int tid = threadIdx.x;
    const int w = tid >> 6, lane = tid & 63;
    const int c = lane & 15, quad = lane >> 4;
    const int m0 = blockIdx.x * 128, n0 = blockIdx.y * 128;
    const int wm = (w >> 1) * 64, wn = (w & 1) * 64;

    floatx4 acc[4][4];
#pragma unroll
    for (int i = 0; i < 4; i++)
#pragma unroll
        for (int j = 0; j < 4; j++) acc[i][j] = (floatx4){0.f, 0.f, 0.f, 0.f};

    for (int kc = 0; kc < K; kc += 64) {
        __syncthreads();
#pragma unroll
        for (int it = 0; it < 4; it++) {
            const int id = it * 256 + tid;
            const int r = id >> 3, c8 = (id & 7) << 3;
            *(uint4*)&As[r][c8] = *(const uint4*)&A[(size_t)(m0 + r) * K + kc + c8];
            *(uint4*)&Bs[r][c8] = *(const uint4*)&Bt[(size_t)(n0 + r) * K + kc + c8];
        }
        __syncthreads();
#pragma unroll
        for (int kk = 0; kk < 2; kk++) {
            short8 af[4], bf[4];
#pragma unroll
            for (int mt = 0; mt < 4; mt++)
                af[mt] = *(const short8*)&As[wm + mt * 16 + c][kk * 32 + quad * 8];
#pragma unroll
            for (int nt = 0; nt < 4; nt++)
                bf[nt] = *(const short8*)&Bs[wn + nt * 16 + c][kk * 32 + quad * 8];
#pragma unroll
            for (int mt = 0; mt < 4; mt++)
#pragma unroll
                for (int nt = 0; nt < 4; nt++)
                    acc[mt][nt] = MFMA16(af[mt], bf[nt], acc[mt][nt]);
        }
    }

#pragma unroll
    for (int nt = 0; nt < 4; nt++) {
        const int n = n0 + wn + nt * 16 + c;
        const float bb = bias[n];
#pragma unroll
        for (int mt = 0; mt < 4; mt++) {
            const int m = m0 + wm + mt * 16 + quad * 4;
#pragma unroll
            for (int r = 0; r < 4; r++) {
                const float val = acc[mt][nt][r] + bb;
                const size_t off = (size_t)(m + r) * N + n;
                if (Cf) Cf[off] = val;
                if (Cb) Cb[off] = f2bf(val);
            }
        }
    }
}

// ---------------------------------------------------------------------------
// threshold[row] = sum_h qb*kb*Wt + bt  (bf16 inputs, fp32 accumulate)
// ---------------------------------------------------------------------------
__global__ __launch_bounds__(256) void threshold_kernel(
    const unsigned short* __restrict__ qb, const unsigned short* __restrict__ kb,
    const float* __restrict__ Wt, const float* __restrict__ bt,
    float* __restrict__ thr)
{
    const int w = threadIdx.x >> 6, lane = threadIdx.x & 63;
    const int row = blockIdx.x * 4 + w;
    const unsigned short* qr = qb + (size_t)row * HID;
    const unsigned short* kr = kb + (size_t)row * HID;
    float s = 0.f;
#pragma unroll
    for (int ii = 0; ii < 2; ii++) {
        const int base = ii * 512 + lane * 8;
        const ushort4 q0 = *(const ushort4*)&qr[base];
        const ushort4 q1 = *(const ushort4*)&qr[base + 4];
        const ushort4 k0 = *(const ushort4*)&kr[base];
        const ushort4 k1 = *(const ushort4*)&kr[base + 4];
        const float4 w0 = *(const float4*)&Wt[base];
        const float4 w1 = *(const float4*)&Wt[base + 4];
        s += bf2f(q0.x) * bf2f(k0.x) * w0.x + bf2f(q0.y) * bf2f(k0.y) * w0.y +
             bf2f(q0.z) * bf2f(k0.z) * w0.z + bf2f(q0.w) * bf2f(k0.w) * w0.w +
             bf2f(q1.x) * bf2f(k1.x) * w1.x + bf2f(q1.y) * bf2f(k1.y) * w1.y +
             bf2f(q1.z) * bf2f(k1.z) * w1.z + bf2f(q1.w) * bf2f(k1.w) * w1.w;
    }
#pragma unroll
    for (int off = 32; off > 0; off >>= 1) s += __shfl_xor(s, off, 64);
    if (lane == 0) thr[row] = s + bt[0];
}

// ---------------------------------------------------------------------------
// Pass 1 (MFMA): per (b,h), 64 q-rows/block. No max-subtraction (|s|<~3).
// V comes pre-transposed (vt[b][h][d][seq]). att written bf16.
// ---------------------------------------------------------------------------
__global__ __launch_bounds__(256) void flash_mfma_kernel(
    const unsigned short* __restrict__ qb, const unsigned short* __restrict__ kb,
    const unsigned short* __restrict__ vt, const unsigned char* __restrict__ mask,
    unsigned short* __restrict__ att, float* __restrict__ zinv_out)
{
    const int b = blockIdx.z, h = blockIdx.y;
    const int q0 = blockIdx.x * 64;
    const int tid = threadIdx.x;
    const int w = tid >> 6, lane = tid & 63;
    const int c = lane & 15, quad = lane >> 4;

    __shared__ unsigned short Qs[64][72];
    __shared__ unsigned short Ks[64][72];
    __shared__ unsigned short Vs[64][72];   // Vs[d][j]
    __shared__ unsigned short Ps[4][16][72];
    __shared__ unsigned char  maskc[64];

    const size_t hoff = (size_t)h * DHEAD;
    for (int g = tid; g < 512; g += 256) {
        const int r = g >> 3, c8 = (g & 7) << 3;
        *(uint4*)&Qs[r][c8] =
            *(const uint4*)&qb[(size_t)(b * SEQ + q0 + r) * HID + hoff + c8];
    }

    floatx4 acc_o[4];
#pragma unroll
    for (int dt = 0; dt < 4; dt++) acc_o[dt] = (floatx4){0.f, 0.f, 0.f, 0.f};
    float zp[4] = {0.f, 0.f, 0.f, 0.f};
    const size_t vtbase = (size_t)(b * NHEAD + h) * DHEAD * SEQ;

    for (int kc = 0; kc < SEQ; kc += 64) {
        __syncthreads();
        for (int g = tid; g < 512; g += 256) {
            const int r = g >> 3, c8 = (g & 7) << 3;
            *(uint4*)&Ks[r][c8] =
                *(const uint4*)&kb[(size_t)(b * SEQ + kc + r) * HID + hoff + c8];
            *(uint4*)&Vs[r][c8] =
                *(const uint4*)&vt[vtbase + (size_t)r * SEQ + kc + c8];
        }
        if (tid < 64) maskc[tid] = mask[(size_t)b * SEQ + kc + tid];
        __syncthreads();

        const short8 aq0 = *(const short8*)&Qs[w * 16 + c][quad * 8];
        const short8 aq1 = *(const short8*)&Qs[w * 16 + c][32 + quad * 8];

#pragma unroll
        for (int nt = 0; nt < 4; nt++) {
            const short8 bk0 = *(const short8*)&Ks[nt * 16 + c][quad * 8];
            const short8 bk1 = *(const short8*)&Ks[nt * 16 + c][32 + quad * 8];
            floatx4 s = (floatx4){0.f, 0.f, 0.f, 0.f};
            s = MFMA16(aq0, bk0, s);
            s = MFMA16(aq1, bk1, s);
            const int mk = maskc[nt * 16 + c];
#pragma unroll
            for (int r = 0; r < 4; r++) {
                const float p = mk ? 0.f : __expf(s[r] * QK_SCALE);
                zp[r] += p;
                Ps[w][quad * 4 + r][nt * 16 + c] = f2bf(p);
            }
        }

        const short8 ap0 = *(const short8*)&Ps[w][c][quad * 8];
        const short8 ap1 = *(const short8*)&Ps[w][c][32 + quad * 8];
#pragma unroll
        for (int dt = 0; dt < 4; dt++) {
            const short8 bv0 = *(const short8*)&Vs[dt * 16 + c][quad * 8];
            const short8 bv1 = *(const short8*)&Vs[dt * 16 + c][32 + quad * 8];
            acc_o[dt] = MFMA16(ap0, bv0, acc_o[dt]);
            acc_o[dt] = MFMA16(ap1, bv1, acc_o[dt]);
        }
    }

#pragma unroll
    for (int r = 0; r < 4; r++) {
        float z = zp[r];
        z += __shfl_xor(z, 1, 64); z += __shfl_xor(z, 2, 64);
        z += __shfl_xor(z, 4, 64); z += __shfl_xor(z, 8, 64);
        zp[r] = 1.0f / (z + 1e-30f);
    }

#pragma unroll
    for (int dt = 0; dt < 4; dt++)
#pragma unroll
        for (int r = 0; r < 4; r++)
            att[(size_t)(b * SEQ + q0 + w * 16 + quad * 4 + r) * HID + hoff +
                dt * 16 + c] = f2bf(acc_o[dt][r] * zp[r]);

    if (c == 0) {
        const size_t zb = (size_t)(b * NHEAD + h) * SEQ + q0 + w * 16 + quad * 4;
#pragma unroll
        for (int r = 0; r < 4; r++) zinv_out[zb + r] = zp[r];
    }
}

// ---------------------------------------------------------------------------
// Pass 2 (MFMA): colsum_k += sum_q exp(s)*zinv_q; atomicAdd over heads.
// ---------------------------------------------------------------------------
__global__ __launch_bounds__(256) void colsum_mfma_kernel(
    const unsigned short* __restrict__ qb, const unsigned short* __restrict__ kb,
    const unsigned char* __restrict__ mask, const float* __restrict__ zinv,
    float* __restrict__ colsum)
{
    const int b = blockIdx.z, h = blockIdx.y, k0 = blockIdx.x * 64;
    const int tid = threadIdx.x;
    const int w = tid >> 6, lane = tid & 63;
    const int c = lane & 15, quad = lane >> 4;

    __shared__ unsigned short Ks[64][72];
    __shared__ unsigned short Qs[64][72];
    __shared__ float zs[64];
    __shared__ unsigned char maskc[64];

    const size_t hoff = (size_t)h * DHEAD;
    for (int g = tid; g < 512; g += 256) {
        const int r = g >> 3, c8 = (g & 7) << 3;
        *(uint4*)&Ks[r][c8] =
            *(const uint4*)&kb[(size_t)(b * SEQ + k0 + r) * HID + hoff + c8];
    }
    if (tid < 64) maskc[tid] = mask[(size_t)b * SEQ + k0 + tid];

    float cs[4] = {0.f, 0.f, 0.f, 0.f};
    const size_t zbase = (size_t)(b * NHEAD + h) * SEQ;

    for (int qc = 0; qc < SEQ; qc += 64) {
        __syncthreads();
        for (int g = tid; g < 512; g += 256) {
            const int r = g >> 3, c8 = (g & 7) << 3;
            *(uint4*)&Qs[r][c8] =
                *(const uint4*)&qb[(size_t)(b * SEQ + qc + r) * HID + hoff + c8];
        }
        if (tid < 64) zs[tid] = zinv[zbase + qc + tid];
        __syncthreads();

        const short8 ak0 = *(const short8*)&Ks[w * 16 + c][quad * 8];
        const short8 ak1 = *(const short8*)&Ks[w * 16 + c][32 + quad * 8];
#pragma unroll
        for (int qt = 0; qt < 4; qt++) {
            const short8 bq0 = *(const short8*)&Qs[qt * 16 + c][quad * 8];
            const short8 bq1 = *(const short8*)&Qs[qt * 16 + c][32 + quad * 8];
            floatx4 s = (floatx4){0.f, 0.f, 0.f, 0.f};
            s = MFMA16(ak0, bq0, s);
            s = MFMA16(ak1, bq1, s);
            const float zi = zs[qt * 16 + c];
#pragma unroll
            for (int r = 0; r < 4; r++) {
                const float p = maskc[w * 16 + quad * 4 + r] ? 0.f
                                : __expf(s[r] * QK_SCALE);
                cs[r] += p * zi;
            }
        }
    }

#pragma unroll
    for (int r = 0; r < 4; r++) {
        float v = cs[r];
        v += __shfl_xor(v, 1, 64); v += __shfl_xor(v, 2, 64);
        v += __shfl_xor(v, 4, 64); v += __shfl_xor(v, 8, 64);
        if (c == 0)
            atomicAdd(&colsum[(size_t)b * SEQ + k0 + w * 16 + quad * 4 + r], v);
    }
}

// ---------------------------------------------------------------------------
// Gate on bf16 att: zero the row if (colsum - thr) <= 0. 2 rows/block.
// ---------------------------------------------------------------------------
__global__ __launch_bounds__(256) void gate_kernel(
    unsigned short* __restrict__ att, const float* __restrict__ colsum,
    const float* __restrict__ thr)
{
    const int row = blockIdx.x * 2 + (threadIdx.x >> 7);
    const int ch = threadIdx.x & 127;
    if ((colsum[row] - thr[row]) > 0.f) return;
    uint4 z; z.x = 0; z.y = 0; z.z = 0; z.w = 0;
    *(uint4*)&att[(size_t)row * HID + ch * 8] = z;
}

// ---------------------------------------------------------------------------
extern "C" void kernel_launch(void* const* d_in, const int* in_sizes, int n_in,
                              void* d_out, int out_size, void* d_ws, size_t ws_size,
                              hipStream_t stream)
{
    const float* v  = (const float*)d_in[0];
    const float* k  = (const float*)d_in[1];
    const float* q  = (const float*)d_in[2];
    const unsigned char* mask = (const unsigned char*)d_in[3];
    const float* Wv = (const float*)d_in[4];
    const float* bv = (const float*)d_in[5];
    const float* Wk = (const float*)d_in[6];
    const float* bk = (const float*)d_in[7];
    const float* Wq = (const float*)d_in[8];
    const float* bq = (const float*)d_in[9];
    const float* Wt = (const float*)d_in[10];
    const float* bt = (const float*)d_in[11];
    const float* Wm = (const float*)d_in[12];
    const float* bm = (const float*)d_in[13];
    float* out = (float*)d_out;

    const size_t NE = (size_t)MROWS * HID;     // 4.19M elems
    const size_t WE = (size_t)HID * HID;       // 1.05M elems
    unsigned short* qa   = (unsigned short*)d_ws;
    unsigned short* ka   = qa  + NE;
    unsigned short* va   = ka  + NE;
    unsigned short* qp   = va  + NE;
    unsigned short* kp   = qp  + NE;
    unsigned short* vp   = kp  + NE;
    unsigned short* WqT  = vp  + NE;
    unsigned short* WkT  = WqT + WE;
    unsigned short* WvT  = WkT + WE;
    unsigned short* WmT  = WvT + WE;
    float* thr    = (float*)(WmT + WE);
    float* zinv   = thr  + MROWS;
    float* colsum = zinv + (size_t)BATCH * NHEAD * SEQ;
    // buffer reuse (stream-ordered, no overlap of live ranges):
    unsigned short* attb = qa;   // qa dead after q-projection GEMM
    unsigned short* vt   = ka;   // ka dead after k-projection GEMM

    const dim3 wg(HID / 64, HID / 64);
    wtrans_kernel<<<wg, 256, 0, stream>>>(Wq, WqT);
    wtrans_kernel<<<wg, 256, 0, stream>>>(Wk, WkT);
    wtrans_kernel<<<wg, 256, 0, stream>>>(Wv, WvT);
    wtrans_kernel<<<wg, 256, 0, stream>>>(Wm, WmT);

    const int cvb = (int)(NE / (256 * 8));
    cvt_bf16_kernel<<<cvb, 256, 0, stream>>>(q, qa);
    cvt_bf16_kernel<<<cvb, 256, 0, stream>>>(k, ka);
    cvt_bf16_kernel<<<cvb, 256, 0, stream>>>(v, va);

    const dim3 gg(MROWS / 128, HID / 128);
    gemm_mfma_kernel<<<gg, 256, 0, stream>>>(qa, WqT, bq, nullptr, qp, MROWS, HID, HID);
    gemm_mfma_kernel<<<gg, 256, 0, stream>>>(ka, WkT, bk, nullptr, kp, MROWS, HID, HID);
    gemm_mfma_kernel<<<gg, 256, 0, stream>>>(va, WvT, bv, nullptr, vp, MROWS, HID, HID);

    vtrans_kernel<<<dim3(SEQ / 64, NHEAD, BATCH), 256, 0, stream>>>(vp, vt);

    threshold_kernel<<<MROWS / 4, 256, 0, stream>>>(qp, kp, Wt, bt, thr);

    flash_mfma_kernel<<<dim3(SEQ / 64, NHEAD, BATCH), 256, 0, stream>>>(
        qp, kp, vt, mask, attb, zinv);

    hipMemsetAsync(colsum, 0, MROWS * sizeof(float), stream);
    colsum_mfma_kernel<<<dim3(SEQ / 64, NHEAD, BATCH), 256, 0, stream>>>(
        qp, kp, mask, zinv, colsum);

    gate_kernel<<<MROWS / 2, 256, 0, stream>>>(attb, colsum, thr);

    gemm_mfma_kernel<<<gg, 256, 0, stream>>>(attb, WmT, bm, out, nullptr, MROWS, HID, HID);
}